// Round 1
// baseline (24.336 us; speedup 1.0000x reference)
//
#include <hip/hip_runtime.h>
#include <math.h>

#define H    1024
#define NH   16
#define HD   128
#define ID   2048                 // NH*HD
#define NROWS_A (3*ID + ID + NH)  // 6144 qkv + 2048 z + 16 a = 8208
#define NSLICE 8
#define DPS  (HD / NSLICE)        // 16 d-rows per slice

__device__ __forceinline__ float waveReduceSum(float v) {
#pragma unroll
    for (int off = 32; off > 0; off >>= 1) v += __shfl_down(v, off, 64);
    return v;
}

// Kernel A: fused matvec of x against W_qkv (6144 rows), W_z (2048), W_a (16).
// One wave (64 lanes) per row; each lane reads 4x float4 (1024 floats/row).
__global__ __launch_bounds__(256) void matvec_qkvza(
    const float* __restrict__ x,
    const float* __restrict__ Wqkv,
    const float* __restrict__ Wz,
    const float* __restrict__ Wa,
    float* __restrict__ ws_qkv,    // [6144]
    float* __restrict__ ws_z,      // [2048]
    float* __restrict__ ws_decay)  // [16] (sigmoid applied)
{
    const int wave = threadIdx.x >> 6;
    const int lane = threadIdx.x & 63;
    const int r = blockIdx.x * 4 + wave;
    if (r >= NROWS_A) return;

    const float* row;
    if (r < 3 * ID)           row = Wqkv + (size_t)r * H;
    else if (r < 3 * ID + ID) row = Wz   + (size_t)(r - 3 * ID) * H;
    else                      row = Wa   + (size_t)(r - 3 * ID - ID) * H;

    const float4* row4 = (const float4*)row;
    const float4* x4   = (const float4*)x;

    float acc = 0.f;
#pragma unroll
    for (int t = 0; t < 4; ++t) {
        float4 w  = row4[lane + 64 * t];
        float4 xv = x4[lane + 64 * t];
        acc += w.x * xv.x + w.y * xv.y + w.z * xv.z + w.w * xv.w;
    }
    acc = waveReduceSum(acc);
    if (lane == 0) {
        if (r < 3 * ID)           ws_qkv[r] = acc;
        else if (r < 3 * ID + ID) ws_z[r - 3 * ID] = acc;
        else                      ws_decay[r - 3 * ID - ID] = 1.f / (1.f + expf(-acc));
    }
}

// Kernel B: new_state = state*decay + k⊗v, plus partial y[h,e] = Σ_d q[d]*new_state[d,e].
// Block = (head h, d-slice s), 128 threads = one output column e each.
// Coalesced: at each d, the 128 threads read/write 128 consecutive floats.
__global__ __launch_bounds__(128) void state_update(
    const float* __restrict__ state_in,
    const float* __restrict__ ws_qkv,
    const float* __restrict__ ws_decay,
    float* __restrict__ state_out,
    float* __restrict__ ws_ypart)   // [NSLICE][NH*HD]
{
    const int h = blockIdx.x / NSLICE;
    const int s = blockIdx.x % NSLICE;
    const int e = threadIdx.x;

    const float decay = ws_decay[h];
    const float* q = ws_qkv + h * HD;
    const float* k = ws_qkv + ID + h * HD;
    const float* v = ws_qkv + 2 * ID + h * HD;
    const float ve = v[e];

    const float* sin_ = state_in  + (size_t)h * HD * HD;
    float*       sout = state_out + (size_t)h * HD * HD;

    float acc = 0.f;
    const int d0 = s * DPS;
#pragma unroll 4
    for (int dd = 0; dd < DPS; ++dd) {
        const int d = d0 + dd;
        const float kd = k[d];   // wave-uniform broadcast
        const float qd = q[d];
        const float sn = sin_[d * HD + e] * decay + kd * ve;
        sout[d * HD + e] = sn;
        acc += qd * sn;
    }
    ws_ypart[s * (NH * HD) + h * HD + e] = acc;
}

// Kernel C: reduce y partials, per-head RMSNorm, silu(z) gate. Block per head.
__global__ __launch_bounds__(128) void norm_gate(
    const float* __restrict__ ws_ypart,
    const float* __restrict__ ws_z,
    const float* __restrict__ norm_w,
    float* __restrict__ ws_gated)   // [2048]
{
    const int h = blockIdx.x;
    const int e = threadIdx.x;

    float y = 0.f;
#pragma unroll
    for (int s = 0; s < NSLICE; ++s) y += ws_ypart[s * (NH * HD) + h * HD + e];

    float s2 = waveReduceSum(y * y);
    __shared__ float red[2];
    const int wave = threadIdx.x >> 6, lane = threadIdx.x & 63;
    if (lane == 0) red[wave] = s2;
    __syncthreads();
    const float total = red[0] + red[1];
    const float scale = rsqrtf(total * (1.f / HD) + 1e-6f);

    const float z   = ws_z[h * HD + e];
    const float sig = 1.f / (1.f + expf(-z));
    ws_gated[h * HD + e] = y * scale * norm_w[e] * (z * sig);
}

// Kernel D: out[i] = dot(gated[2048], W_out[i,:]). Wave per row, 8 float4/lane.
__global__ __launch_bounds__(256) void matvec_out(
    const float* __restrict__ gated,
    const float* __restrict__ Wout,
    float* __restrict__ out)
{
    const int wave = threadIdx.x >> 6;
    const int lane = threadIdx.x & 63;
    const int r = blockIdx.x * 4 + wave;   // 0..1023

    const float4* row4 = (const float4*)(Wout + (size_t)r * ID);
    const float4* g4   = (const float4*)gated;

    float acc = 0.f;
#pragma unroll
    for (int t = 0; t < 8; ++t) {
        float4 w = row4[lane + 64 * t];
        float4 g = g4[lane + 64 * t];
        acc += w.x * g.x + w.y * g.y + w.z * g.z + w.w * g.w;
    }
    acc = waveReduceSum(acc);
    if (lane == 0) out[r] = acc;
}

extern "C" void kernel_launch(void* const* d_in, const int* in_sizes, int n_in,
                              void* d_out, int out_size, void* d_ws, size_t ws_size,
                              hipStream_t stream) {
    const float* x     = (const float*)d_in[0];
    const float* state = (const float*)d_in[1];
    const float* conv  = (const float*)d_in[2];
    const float* Wqkv  = (const float*)d_in[3];
    const float* Wz    = (const float*)d_in[4];
    const float* Wa    = (const float*)d_in[5];
    const float* normw = (const float*)d_in[6];
    const float* Wout  = (const float*)d_in[7];

    float* out       = (float*)d_out;                 // [1024]
    float* new_state = out + H;                       // [16*128*128]
    float* conv_out  = new_state + (size_t)NH * HD * HD; // [18432]

    float* ws       = (float*)d_ws;
    float* ws_qkv   = ws;              // 6144
    float* ws_z     = ws + 6144;       // 2048
    float* ws_decay = ws + 8192;       // 16
    float* ws_ypart = ws + 8208;       // 8*2048
    float* ws_gated = ws + 8208 + NSLICE * (NH * HD); // 2048

    // conv_state passthrough
    hipMemcpyAsync(conv_out, conv, (size_t)(3 * ID * 3) * sizeof(float),
                   hipMemcpyDeviceToDevice, stream);

    matvec_qkvza<<<NROWS_A / 4, 256, 0, stream>>>(x, Wqkv, Wz, Wa, ws_qkv, ws_z, ws_decay);
    state_update<<<NH * NSLICE, 128, 0, stream>>>(state, ws_qkv, ws_decay, new_state, ws_ypart);
    norm_gate<<<NH, 128, 0, stream>>>(ws_ypart, ws_z, normw, ws_gated);
    matvec_out<<<H / 4, 256, 0, stream>>>(ws_gated, Wout, out);
}

// Round 2
// 18.520 us; speedup vs baseline: 1.3140x; 1.3140x over previous
//
#include <hip/hip_runtime.h>
#include <math.h>

#define H    1024
#define NH   16
#define HD   128
#define ID   2048                 // NH*HD
#define NROWS_A (3*ID + ID + NH)  // 6144 qkv + 2048 z + 16 a = 8208
#define MATVEC_BLOCKS (NROWS_A / 4)   // 2052
#define CONV_FLOATS (3 * ID * 3)      // 18432 floats = 4608 float4
#define CONV_BLOCKS (CONV_FLOATS / 4 / 256)  // 18
#define EPS 1e-6f

__device__ __forceinline__ float waveReduceSum(float v) {
#pragma unroll
    for (int off = 32; off > 0; off >>= 1) v += __shfl_down(v, off, 64);
    return v;
}

// Kernel 1: fused matvec of x against W_qkv (6144 rows), W_z (2048), W_a (16),
// plus conv_state passthrough copy in trailing blocks.
// One wave (64 lanes) per row; each lane reads 4x float4 (1024 floats/row).
__global__ __launch_bounds__(256) void matvec_qkvza(
    const float* __restrict__ x,
    const float* __restrict__ Wqkv,
    const float* __restrict__ Wz,
    const float* __restrict__ Wa,
    const float* __restrict__ conv,
    float* __restrict__ conv_out,
    float* __restrict__ ws_qkv,    // [6144]
    float* __restrict__ ws_z,      // [2048]
    float* __restrict__ ws_decay)  // [16] (sigmoid applied)
{
    if (blockIdx.x >= MATVEC_BLOCKS) {
        // conv_state copy blocks: one float4 per thread
        const int i = (blockIdx.x - MATVEC_BLOCKS) * 256 + threadIdx.x;
        ((float4*)conv_out)[i] = ((const float4*)conv)[i];
        return;
    }

    const int wave = threadIdx.x >> 6;
    const int lane = threadIdx.x & 63;
    const int r = blockIdx.x * 4 + wave;

    const float* row;
    if (r < 3 * ID)           row = Wqkv + (size_t)r * H;
    else if (r < 3 * ID + ID) row = Wz   + (size_t)(r - 3 * ID) * H;
    else                      row = Wa   + (size_t)(r - 3 * ID - ID) * H;

    const float4* row4 = (const float4*)row;
    const float4* x4   = (const float4*)x;

    float acc = 0.f;
#pragma unroll
    for (int t = 0; t < 4; ++t) {
        float4 w  = row4[lane + 64 * t];
        float4 xv = x4[lane + 64 * t];
        acc += w.x * xv.x + w.y * xv.y + w.z * xv.z + w.w * xv.w;
    }
    acc = waveReduceSum(acc);
    if (lane == 0) {
        if (r < 3 * ID)           ws_qkv[r] = acc;
        else if (r < 3 * ID + ID) ws_z[r - 3 * ID] = acc;
        else                      ws_decay[r - 3 * ID - ID] = 1.f / (1.f + expf(-acc));
    }
}

// Kernel 2: per head (one block of 1024 threads):
//   new_state = state*decay + k (outer) v      (written to d_out)
//   y[e] = sum_d q[d] * new_state[d,e]         (LDS reduce over 32 d-groups)
//   RMSNorm over e, silu(z) gate               (first 128 threads)
// Thread layout: c = tid&31 (float4 column, e = 4c..4c+3), g = tid>>5 (d-group of 4).
__global__ __launch_bounds__(1024) void state_norm_gate(
    const float* __restrict__ state_in,
    const float* __restrict__ ws_qkv,
    const float* __restrict__ ws_decay,
    const float* __restrict__ ws_z,
    const float* __restrict__ norm_w,
    float* __restrict__ state_out,
    float* __restrict__ ws_gated)   // [2048]
{
    const int h = blockIdx.x;
    const int tid = threadIdx.x;
    const int c = tid & 31;
    const int g = tid >> 5;

    const float decay = ws_decay[h];
    const float* q  = ws_qkv + h * HD;
    const float* k  = ws_qkv + ID + h * HD;
    const float4 vv = ((const float4*)(ws_qkv + 2 * ID + h * HD))[c];

    const float4* sin4 = (const float4*)(state_in  + (size_t)h * HD * HD);
    float4*       sout = (float4*)(state_out + (size_t)h * HD * HD);

    float4 acc = {0.f, 0.f, 0.f, 0.f};
#pragma unroll
    for (int i = 0; i < 4; ++i) {
        const int d = g * 4 + i;
        const float kd = k[d];
        const float qd = q[d];
        float4 s = sin4[d * 32 + c];
        float4 sn;
        sn.x = s.x * decay + kd * vv.x;
        sn.y = s.y * decay + kd * vv.y;
        sn.z = s.z * decay + kd * vv.z;
        sn.w = s.w * decay + kd * vv.w;
        sout[d * 32 + c] = sn;
        acc.x += qd * sn.x;
        acc.y += qd * sn.y;
        acc.z += qd * sn.z;
        acc.w += qd * sn.w;
    }

    __shared__ float part[32][HD];   // 16 KB
    part[g][4 * c + 0] = acc.x;
    part[g][4 * c + 1] = acc.y;
    part[g][4 * c + 2] = acc.z;
    part[g][4 * c + 3] = acc.w;
    __syncthreads();

    __shared__ float red[2];
    float y = 0.f;
    if (tid < HD) {
#pragma unroll
        for (int g2 = 0; g2 < 32; ++g2) y += part[g2][tid];
        float s2 = waveReduceSum(y * y);
        if ((tid & 63) == 0) red[tid >> 6] = s2;
    }
    __syncthreads();
    if (tid < HD) {
        const float total = red[0] + red[1];
        const float scale = rsqrtf(total * (1.f / HD) + EPS);
        const float z   = ws_z[h * HD + tid];
        const float sig = 1.f / (1.f + expf(-z));
        ws_gated[h * HD + tid] = y * scale * norm_w[tid] * (z * sig);
    }
}

// Kernel 3: out[i] = dot(gated[2048], W_out[i,:]). Wave per row, 8 float4/lane.
__global__ __launch_bounds__(256) void matvec_out(
    const float* __restrict__ gated,
    const float* __restrict__ Wout,
    float* __restrict__ out)
{
    const int wave = threadIdx.x >> 6;
    const int lane = threadIdx.x & 63;
    const int r = blockIdx.x * 4 + wave;   // 0..1023

    const float4* row4 = (const float4*)(Wout + (size_t)r * ID);
    const float4* g4   = (const float4*)gated;

    float acc = 0.f;
#pragma unroll
    for (int t = 0; t < 8; ++t) {
        float4 w = row4[lane + 64 * t];
        float4 g = g4[lane + 64 * t];
        acc += w.x * g.x + w.y * g.y + w.z * g.z + w.w * g.w;
    }
    acc = waveReduceSum(acc);
    if (lane == 0) out[r] = acc;
}

extern "C" void kernel_launch(void* const* d_in, const int* in_sizes, int n_in,
                              void* d_out, int out_size, void* d_ws, size_t ws_size,
                              hipStream_t stream) {
    const float* x     = (const float*)d_in[0];
    const float* state = (const float*)d_in[1];
    const float* conv  = (const float*)d_in[2];
    const float* Wqkv  = (const float*)d_in[3];
    const float* Wz    = (const float*)d_in[4];
    const float* Wa    = (const float*)d_in[5];
    const float* normw = (const float*)d_in[6];
    const float* Wout  = (const float*)d_in[7];

    float* out       = (float*)d_out;                    // [1024]
    float* new_state = out + H;                          // [16*128*128]
    float* conv_out  = new_state + (size_t)NH * HD * HD; // [18432]

    float* ws       = (float*)d_ws;
    float* ws_qkv   = ws;              // 6144
    float* ws_z     = ws + 6144;       // 2048
    float* ws_decay = ws + 8192;       // 16
    float* ws_gated = ws + 8208;       // 2048 (16B-aligned: 8208*4 % 16 == 0)

    matvec_qkvza<<<MATVEC_BLOCKS + CONV_BLOCKS, 256, 0, stream>>>(
        x, Wqkv, Wz, Wa, conv, conv_out, ws_qkv, ws_z, ws_decay);
    state_norm_gate<<<NH, 1024, 0, stream>>>(
        state, ws_qkv, ws_decay, ws_z, normw, new_state, ws_gated);
    matvec_out<<<H / 4, 256, 0, stream>>>(ws_gated, Wout, out);
}